// Round 7
// baseline (42.827 us; speedup 1.0000x reference)
//
#include <hip/hip_runtime.h>
#include <math.h>

#define VOCAB 50257
#define BSZ   64
#define BEAM  8
#define NG    4     // NUM_GROUPS
#define MB    2     // beams per group
#define KC    2     // candidates per group
#define TLEN  128
#define NGRAM 2
#define SEGLEN 786               // 64*786 = 50304 >= 50257
#define QSEG  16                 // segments per quarter-block
#define NQ    4                  // quarter-blocks per row
#define ROWS  (BSZ * BEAM)       // 512
#define CAPQ  256                // candidate capacity per quarter (E ~ 20)

__device__ __forceinline__ bool better(float v1, int i1, float v2, int i2) {
    return (v1 > v2) || (v1 == v2 && i1 < i2);
}

struct Top2 { float v1, v2; int i1, i2; };

__device__ __forceinline__ void t2_init(Top2& t) {
    t.v1 = -INFINITY; t.v2 = -INFINITY; t.i1 = 0x7FFFFFFF; t.i2 = 0x7FFFFFFF;
}

__device__ __forceinline__ void t2_push(Top2& t, float v, int i) {
    if (better(v, i, t.v2, t.i2)) {
        if (better(v, i, t.v1, t.i1)) { t.v2 = t.v1; t.i2 = t.i1; t.v1 = v; t.i1 = i; }
        else                          { t.v2 = v;    t.i2 = i; }
    }
}

__device__ __forceinline__ void t2_merge(Top2& a, const Top2& b) {
    if (better(b.v1, b.i1, a.v1, a.i1)) {
        float nv2; int ni2;
        if (better(a.v1, a.i1, b.v2, b.i2)) { nv2 = a.v1; ni2 = a.i1; }
        else                                { nv2 = b.v2; ni2 = b.i2; }
        a.v1 = b.v1; a.i1 = b.i1; a.v2 = nv2; a.i2 = ni2;
    } else {
        if (better(b.v1, b.i1, a.v2, a.i2)) { a.v2 = b.v1; a.i2 = b.i1; }
    }
}

__device__ __forceinline__ float max4(float4 v) {
    return fmaxf(fmaxf(v.x, v.y), fmaxf(v.z, v.w));
}

// ---- K0: compact valid row ids -> wl[0]=nvalid, wl[1..] = row ids ----------
__global__ __launch_bounds__(512) void dbs_worklist(
    const int* __restrict__ mask,   // (512, 2)
    int* __restrict__ wl)
{
    const int tid = threadIdx.x;    // == row id, 0..511
    const int w   = tid >> 6, lane = tid & 63;
    __shared__ int s_wcnt[8];
    __shared__ int s_woff[8];

    const int2 mk = *(const int2*)(mask + tid * NGRAM);
    const bool valid = (mk.x + mk.y) == NGRAM;
    const unsigned long long bm = __ballot(valid);
    if (lane == 0) s_wcnt[w] = __popcll(bm);
    __syncthreads();
    if (tid == 0) {
        int off = 0;
        #pragma unroll
        for (int i = 0; i < 8; ++i) { s_woff[i] = off; off += s_wcnt[i]; }
        wl[0] = off;
    }
    __syncthreads();
    if (valid) {
        const int rank = __popcll(bm & ((1ull << lane) - 1ull));
        wl[1 + s_woff[w] + rank] = tid;
    }
}

// ---- K1: block = (valid-row worklist entry, quarter); segmax->tau->compact -
__global__ __launch_bounds__(256) void dbs_candidates(
    const float* __restrict__ lprobs,   // (512, 50257)
    const int*   __restrict__ wl,
    int*   __restrict__ wscnt,          // (512*4,)
    float* __restrict__ wscv,           // (512*4, CAPQ)
    int*   __restrict__ wsci)           // (512*4, CAPQ)
{
    const int blk = blockIdx.x;         // 2048
    const int i   = blk >> 2;
    const int q   = blk & 3;
    if (i >= wl[0]) return;             // beyond valid work: one cached scalar
    const int r   = wl[1 + i];

    const int tid  = threadIdx.x;
    const int w    = tid >> 6, lane = tid & 63;

    __shared__ float s_max[QSEG];
    __shared__ float s_tau;
    __shared__ int   s_cnt;
    __shared__ float s_cv[CAPQ];
    __shared__ int   s_ci[CAPQ];
    if (tid == 0) s_cnt = 0;

    const size_t rowoff = (size_t)r * VOCAB;
    const float* row = lprobs + rowoff;

    // ---- pass 1: per-segment max (wave w owns 4 consecutive segments) ----
    #pragma unroll
    for (int s = 0; s < 4; ++s) {
        const int lseg  = w * 4 + s;                 // 0..15 within quarter
        const int start = (q * QSEG + lseg) * SEGLEN;
        const int end   = min(start + SEGLEN, VOCAB);
        const int mis   = (int)((rowoff + start) & 3);
        const int pre   = (4 - mis) & 3;

        float m = -INFINITY;
        if (lane < pre && start + lane < end) m = row[start + lane];
        const int vstart = start + pre;
        const int n4 = (end > vstart) ? ((end - vstart) >> 2) : 0;   // <= 196
        const float4* vrow = (const float4*)(row + vstart);

        float a0 = -INFINITY, a1 = -INFINITY, a2 = -INFINITY, a3 = -INFINITY;
        if (lane       < n4) a0 = max4(vrow[lane]);
        if (lane +  64 < n4) a1 = max4(vrow[lane + 64]);
        if (lane + 128 < n4) a2 = max4(vrow[lane + 128]);
        if (lane + 192 < n4) a3 = max4(vrow[lane + 192]);
        m = fmaxf(m, fmaxf(fmaxf(a0, a1), fmaxf(a2, a3)));
        const int tstart = vstart + 4 * n4;
        if (tstart + lane < end) m = fmaxf(m, row[tstart + lane]);

        #pragma unroll
        for (int off = 32; off > 0; off >>= 1) m = fmaxf(m, __shfl_xor(m, off));
        if (lane == 0) s_max[lseg] = m;
    }
    __syncthreads();

    // ---- tau = 8th largest (lex) of the 16 segment maxima (wave 0) ----
    // >=8 elements of this quarter are >= tau => quarter top-8 all >= tau
    // => union over quarters of {v >= tau_q} contains row top-8 superset.
    if (w == 0) {
        const float mym = (lane < QSEG) ? s_max[lane] : -INFINITY;
        int rank = 0;
        #pragma unroll
        for (int ii = 0; ii < QSEG; ++ii) {
            const float om = __shfl(mym, ii);
            rank += better(om, ii, mym, lane) ? 1 : 0;
        }
        if (lane < QSEG && rank == 7) s_tau = mym;  // ranks form a permutation
    }
    __syncthreads();
    const float tau = s_tau;

    // ---- pass 2: rescan (L2-resident), compact v >= tau into LDS ----
    #pragma unroll
    for (int s = 0; s < 4; ++s) {
        const int lseg  = w * 4 + s;
        const int start = (q * QSEG + lseg) * SEGLEN;
        const int end   = min(start + SEGLEN, VOCAB);
        const int mis   = (int)((rowoff + start) & 3);
        const int pre   = (4 - mis) & 3;

        if (lane < pre && start + lane < end) {
            const float v = row[start + lane];
            if (v >= tau) {
                const int p = atomicAdd(&s_cnt, 1);
                if (p < CAPQ) { s_cv[p] = v; s_ci[p] = start + lane; }
            }
        }
        const int vstart = start + pre;
        const int n4 = (end > vstart) ? ((end - vstart) >> 2) : 0;
        const float4* vrow = (const float4*)(row + vstart);

        #pragma unroll
        for (int u = 0; u < 4; ++u) {
            const int jj = lane + u * 64;
            if (jj < n4) {
                const float4 v = vrow[jj];
                if (max4(v) >= tau) {
                    const int base = vstart + 4 * jj;
                    #pragma unroll
                    for (int e = 0; e < 4; ++e) {
                        const float ve = (e == 0) ? v.x : (e == 1) ? v.y
                                       : (e == 2) ? v.z : v.w;
                        if (ve >= tau) {
                            const int p = atomicAdd(&s_cnt, 1);
                            if (p < CAPQ) { s_cv[p] = ve; s_ci[p] = base + e; }
                        }
                    }
                }
            }
        }
        const int tstart = vstart + 4 * n4;
        if (tstart + lane < end) {
            const float v = row[tstart + lane];
            if (v >= tau) {
                const int p = atomicAdd(&s_cnt, 1);
                if (p < CAPQ) { s_cv[p] = v; s_ci[p] = tstart + lane; }
            }
        }
    }
    __syncthreads();

    // ---- emit: count + coalesced candidate dump (per-quarter slot) ----
    const int cnt  = min(s_cnt, CAPQ);
    const int slot = r * NQ + q;
    if (tid == 0) wscnt[slot] = cnt;
    for (int c = tid; c < cnt; c += 256) {
        wscv[(size_t)slot * CAPQ + c] = s_cv[c];
        wsci[(size_t)slot * CAPQ + c] = s_ci[c];
    }
}

// ---- K2: per-batch sequential group chain on candidates --------------------
__global__ __launch_bounds__(64) void dbs_final(
    const float* __restrict__ scores,   // (64,8,128)
    const float* __restrict__ overlap,  // (64,4,4)
    const int*   __restrict__ obi,      // (64,)
    const int*   __restrict__ lastn,    // (64,8,1)
    const int*   __restrict__ mask,     // (64,8,2)
    const int*   __restrict__ stepp,    // (1,)
    const int*   __restrict__ wscnt,
    const float* __restrict__ wscv,
    const int*   __restrict__ wsci,
    float*       __restrict__ out)      // 2560 floats
{
    const int b   = blockIdx.x;
    const int tid = threadIdx.x;
    const int step = stepp[0];
    const int ob   = obi[b];

    __shared__ float s_sc[BEAM];
    __shared__ int   s_valid[BEAM];
    __shared__ float s_pen[(NG-1)*KC];
    __shared__ int   s_penidx[(NG-1)*KC];
    __shared__ float s_selv[NG][KC];
    __shared__ int   s_seli[NG][KC];
    __shared__ int   s_selm[NG][KC];

    if (tid < BEAM) {
        const int* mk = mask + ((size_t)b * BEAM + tid) * NGRAM;
        s_valid[tid] = (mk[0] + mk[1]) == NGRAM;
        s_sc[tid]    = scores[((size_t)b * BEAM + tid) * TLEN + (step - 1)];
    }
    __syncthreads();

    for (int g = 0; g < NG; ++g) {
        if (tid == 0) {
            for (int j = 0; j < g; ++j) {
                const float pen = 1.0f + overlap[((size_t)ob * NG + g) * NG + j];
                s_penidx[j*KC + 0] = s_seli[j][0]; s_pen[j*KC + 0] = pen;
                s_penidx[j*KC + 1] = s_seli[j][1]; s_pen[j*KC + 1] = pen;
            }
        }
        __syncthreads();

        const int np = KC * g;            // block-uniform
        Top2 t; t2_init(t);
        for (int m = 0; m < MB; ++m) {
            const int beam = m * NG + g;
            if (s_valid[beam]) {          // block-uniform branch
                const int r = b * BEAM + beam;
                for (int qq = 0; qq < NQ; ++qq) {
                    const int slot = r * NQ + qq;
                    const int n = wscnt[slot];
                    for (int c = tid; c < n; c += 64) {
                        const float v   = wscv[(size_t)slot * CAPQ + c];
                        const int   idx = wsci[(size_t)slot * CAPQ + c];
                        float dv = 0.0f;
                        #pragma unroll
                        for (int p = 0; p < (NG-1)*KC; ++p)
                            if (p < np && s_penidx[p] == idx) dv += s_pen[p];
                        t2_push(t, v - 0.5f * dv + s_sc[beam], m * VOCAB + idx);
                    }
                }
            } else if (tid < KC) {
                // invalid row: constant sc -> best two flat idx m*V, m*V+1
                t2_push(t, s_sc[beam], m * VOCAB + tid);
            }
        }

        #pragma unroll
        for (int off = 32; off > 0; off >>= 1) {
            Top2 o;
            o.v1 = __shfl_down(t.v1, off); o.i1 = __shfl_down(t.i1, off);
            o.v2 = __shfl_down(t.v2, off); o.i2 = __shfl_down(t.i2, off);
            t2_merge(t, o);
        }
        if (tid == 0) {
            s_selv[g][0] = t.v1; s_seli[g][0] = t.i1 % VOCAB; s_selm[g][0] = t.i1 / VOCAB;
            s_selv[g][1] = t.v2; s_seli[g][1] = t.i2 % VOCAB; s_selm[g][1] = t.i2 / VOCAB;
        }
        __syncthreads();
    }

    // ---- outputs: scores[0,512) indices[512,1024) beams[1024,1536) overlap[1536,2560)
    if (tid < KC * NG) {                  // i = m*NG + g
        const int i = tid;
        const int m = i / NG, g = i % NG;
        out[(size_t)b * BEAM + i]        = s_selv[g][m];
        out[512 + (size_t)b * BEAM + i]  = (float)s_seli[g][m];
        out[1024 + (size_t)b * BEAM + i] = (float)(s_selm[g][m] * NG + g);
    }
    if (tid >= 16 && tid < 16 + NG * NG) {
        const int q  = tid - 16;
        const int g1 = q / NG, g2 = q % NG;
        int ov = 0;
        for (int m = 0; m < MB; ++m) {
            const int i1 = m * NG + g1, i2 = m * NG + g2;
            const int p1a = lastn[(size_t)b * BEAM + i1];
            const int p2a = lastn[(size_t)b * BEAM + i2];
            const int p1b = s_seli[g1][m];
            const int p2b = s_seli[g2][m];
            const int* mk1 = mask + ((size_t)b * BEAM + i1) * NGRAM;
            const int* mk2 = mask + ((size_t)b * BEAM + i2) * NGRAM;
            const bool e0 = (p1a == p2a) && (mk1[0] != 0) && (mk2[0] != 0);
            const bool e1 = (p1b == p2b) && (mk1[1] != 0) && (mk2[1] != 0);
            ov += (e0 && e1) ? 1 : 0;
        }
        out[1536 + (size_t)ob * (NG * NG) + q] =
            (overlap[(size_t)ob * (NG * NG) + q] + (float)ov) * 0.5f;
    }
}

extern "C" void kernel_launch(void* const* d_in, const int* in_sizes, int n_in,
                              void* d_out, int out_size, void* d_ws, size_t ws_size,
                              hipStream_t stream) {
    const float* lprobs  = (const float*)d_in[0];
    const float* scores  = (const float*)d_in[1];
    const float* overlap = (const float*)d_in[2];
    const int*   obi     = (const int*)d_in[3];
    const int*   lastn   = (const int*)d_in[4];
    const int*   mask    = (const int*)d_in[5];
    const int*   stepp   = (const int*)d_in[6];
    float*       out     = (float*)d_out;

    // ws layout: wl (1024 i32 = 4KB) | wscnt (2048 i32) | wscv | wsci
    int*   wl    = (int*)d_ws;
    int*   wscnt = (int*)((char*)d_ws + 4096);
    float* wscv  = (float*)((char*)d_ws + 4096 + (size_t)ROWS * NQ * 4);
    int*   wsci  = (int*)((char*)d_ws + 4096 + (size_t)ROWS * NQ * 4
                          + (size_t)ROWS * NQ * CAPQ * 4);

    dbs_worklist  <<<1, 512, 0, stream>>>(mask, wl);
    dbs_candidates<<<ROWS * NQ, 256, 0, stream>>>(lprobs, wl, wscnt, wscv, wsci);
    dbs_final     <<<BSZ, 64, 0, stream>>>(scores, overlap, obi, lastn, mask, stepp,
                                           wscnt, wscv, wsci, out);
}

// Round 9
// 35.588 us; speedup vs baseline: 1.2034x; 1.2034x over previous
//
#include <hip/hip_runtime.h>
#include <math.h>

#define VOCAB 50257
#define BSZ   64
#define BEAM  8
#define NG    4     // NUM_GROUPS
#define MB    2     // beams per group
#define KC    2     // candidates per group
#define TLEN  128
#define NGRAM 2
#define SEGLEN 786               // 64*786 = 50304 >= 50257
#define QSEG  16                 // segments per quarter-block
#define NQ    4                  // quarter-blocks per row
#define ROWS  (BSZ * BEAM)       // 512
#define CAPQ  256                // candidate capacity per quarter (E ~ 8-20)

__device__ __forceinline__ bool better(float v1, int i1, float v2, int i2) {
    return (v1 > v2) || (v1 == v2 && i1 < i2);
}

struct Top2 { float v1, v2; int i1, i2; };

__device__ __forceinline__ void t2_init(Top2& t) {
    t.v1 = -INFINITY; t.v2 = -INFINITY; t.i1 = 0x7FFFFFFF; t.i2 = 0x7FFFFFFF;
}

__device__ __forceinline__ void t2_push(Top2& t, float v, int i) {
    if (better(v, i, t.v2, t.i2)) {
        if (better(v, i, t.v1, t.i1)) { t.v2 = t.v1; t.i2 = t.i1; t.v1 = v; t.i1 = i; }
        else                          { t.v2 = v;    t.i2 = i; }
    }
}

__device__ __forceinline__ void t2_merge(Top2& a, const Top2& b) {
    if (better(b.v1, b.i1, a.v1, a.i1)) {
        float nv2; int ni2;
        if (better(a.v1, a.i1, b.v2, b.i2)) { nv2 = a.v1; ni2 = a.i1; }
        else                                { nv2 = b.v2; ni2 = b.i2; }
        a.v1 = b.v1; a.i1 = b.i1; a.v2 = nv2; a.i2 = ni2;
    } else {
        if (better(b.v1, b.i1, a.v2, a.i2)) { a.v2 = b.v1; a.i2 = b.i1; }
    }
}

__device__ __forceinline__ float max4(float4 v) {
    return fmaxf(fmaxf(v.x, v.y), fmaxf(v.z, v.w));
}

// ---- K1: block = (valid-row ordinal, quarter); self-worklist from mask -----
// __launch_bounds__(256, 8): cap VGPR<=64 so all 2048 blocks are co-resident
// (R6 post-mortem: uncapped VGPR -> ~5 blocks/CU -> second dispatch round).
__global__ __launch_bounds__(256, 8) void dbs_candidates(
    const float* __restrict__ lprobs,   // (512, 50257)
    const int*   __restrict__ mask,     // (512, 2)
    int*   __restrict__ wscnt,          // (512*4,)
    float* __restrict__ wscv,           // (512*4, CAPQ)
    int*   __restrict__ wsci)           // (512*4, CAPQ)
{
    const int tid  = threadIdx.x;
    const int w    = tid >> 6, lane = tid & 63;

    __shared__ unsigned s_vbits[ROWS / 32];   // 512-bit validity mask
    __shared__ int   s_row;
    __shared__ float s_max[QSEG];
    __shared__ float s_tau;
    __shared__ int   s_cnt;
    __shared__ float s_cv[CAPQ];
    __shared__ int   s_ci[CAPQ];

    if (tid < ROWS / 32) s_vbits[tid] = 0;
    if (tid == 0) s_cnt = 0;
    __syncthreads();

    // each thread classifies rows 2*tid, 2*tid+1 (one int4 = two mask pairs)
    const int4 mk2 = ((const int4*)mask)[tid];
    unsigned bits = 0;
    if (mk2.x + mk2.y == NGRAM) bits |= 1u;
    if (mk2.z + mk2.w == NGRAM) bits |= 2u;
    if (bits) atomicOr(&s_vbits[tid >> 4], bits << ((2 * tid) & 31));
    __syncthreads();

    // map blockIdx>>2 -> the vidx-th valid row (tid 0 scans 16 words)
    const int vidx = blockIdx.x >> 2;
    const int q    = blockIdx.x & 3;
    if (tid == 0) {
        int cnt = 0, r = -1;
        #pragma unroll
        for (int wd = 0; wd < ROWS / 32; ++wd) {
            const unsigned x = s_vbits[wd];
            const int c = __popc(x);
            if (cnt + c > vidx) {
                unsigned y = x;
                for (int need = vidx - cnt; need > 0; --need) y &= y - 1;
                r = wd * 32 + __ffs(y) - 1;
                break;
            }
            cnt += c;
        }
        s_row = r;
    }
    __syncthreads();
    const int r = s_row;
    if (r < 0) return;                  // beyond valid work

    const size_t rowoff = (size_t)r * VOCAB;
    const float* row = lprobs + rowoff;

    // ---- pass 1: per-segment max (wave w owns 4 consecutive segments) ----
    #pragma unroll
    for (int s = 0; s < 4; ++s) {
        const int lseg  = w * 4 + s;                 // 0..15 within quarter
        const int start = (q * QSEG + lseg) * SEGLEN;
        const int end   = min(start + SEGLEN, VOCAB);
        const int mis   = (int)((rowoff + start) & 3);
        const int pre   = (4 - mis) & 3;

        float m = -INFINITY;
        if (lane < pre && start + lane < end) m = row[start + lane];
        const int vstart = start + pre;
        const int n4 = (end > vstart) ? ((end - vstart) >> 2) : 0;   // <= 196
        const float4* vrow = (const float4*)(row + vstart);

        float a0 = -INFINITY, a1 = -INFINITY, a2 = -INFINITY, a3 = -INFINITY;
        if (lane       < n4) a0 = max4(vrow[lane]);
        if (lane +  64 < n4) a1 = max4(vrow[lane + 64]);
        if (lane + 128 < n4) a2 = max4(vrow[lane + 128]);
        if (lane + 192 < n4) a3 = max4(vrow[lane + 192]);
        m = fmaxf(m, fmaxf(fmaxf(a0, a1), fmaxf(a2, a3)));
        const int tstart = vstart + 4 * n4;
        if (tstart + lane < end) m = fmaxf(m, row[tstart + lane]);

        #pragma unroll
        for (int off = 32; off > 0; off >>= 1) m = fmaxf(m, __shfl_xor(m, off));
        if (lane == 0) s_max[lseg] = m;
    }
    __syncthreads();

    // ---- tau = 8th largest (lex) of the 16 segment maxima (wave 0) ----
    // >=8 elements of this quarter are >= tau => quarter top-8 all >= tau
    // => union over quarters of {v >= tau_q} contains the row top-8.
    if (w == 0) {
        const float mym = (lane < QSEG) ? s_max[lane] : -INFINITY;
        int rank = 0;
        #pragma unroll
        for (int ii = 0; ii < QSEG; ++ii) {
            const float om = __shfl(mym, ii);
            rank += better(om, ii, mym, lane) ? 1 : 0;
        }
        if (lane < QSEG && rank == 7) s_tau = mym;  // ranks form a permutation
    }
    __syncthreads();
    const float tau = s_tau;

    // ---- pass 2: rescan only segments whose max >= tau (~8 of 16) ----
    #pragma unroll
    for (int s = 0; s < 4; ++s) {
        const int lseg  = w * 4 + s;
        if (s_max[lseg] < tau) continue;             // wave-uniform skip, exact
        const int start = (q * QSEG + lseg) * SEGLEN;
        const int end   = min(start + SEGLEN, VOCAB);
        const int mis   = (int)((rowoff + start) & 3);
        const int pre   = (4 - mis) & 3;

        if (lane < pre && start + lane < end) {
            const float v = row[start + lane];
            if (v >= tau) {
                const int p = atomicAdd(&s_cnt, 1);
                if (p < CAPQ) { s_cv[p] = v; s_ci[p] = start + lane; }
            }
        }
        const int vstart = start + pre;
        const int n4 = (end > vstart) ? ((end - vstart) >> 2) : 0;
        const float4* vrow = (const float4*)(row + vstart);

        #pragma unroll
        for (int u = 0; u < 4; ++u) {
            const int jj = lane + u * 64;
            if (jj < n4) {
                const float4 v = vrow[jj];
                if (max4(v) >= tau) {
                    const int base = vstart + 4 * jj;
                    #pragma unroll
                    for (int e = 0; e < 4; ++e) {
                        const float ve = (e == 0) ? v.x : (e == 1) ? v.y
                                       : (e == 2) ? v.z : v.w;
                        if (ve >= tau) {
                            const int p = atomicAdd(&s_cnt, 1);
                            if (p < CAPQ) { s_cv[p] = ve; s_ci[p] = base + e; }
                        }
                    }
                }
            }
        }
        const int tstart = vstart + 4 * n4;
        if (tstart + lane < end) {
            const float v = row[tstart + lane];
            if (v >= tau) {
                const int p = atomicAdd(&s_cnt, 1);
                if (p < CAPQ) { s_cv[p] = v; s_ci[p] = tstart + lane; }
            }
        }
    }
    __syncthreads();

    // ---- emit: count + coalesced candidate dump (per-quarter slot) ----
    const int cnt  = min(s_cnt, CAPQ);
    const int slot = r * NQ + q;
    if (tid == 0) wscnt[slot] = cnt;
    for (int c = tid; c < cnt; c += 256) {
        wscv[(size_t)slot * CAPQ + c] = s_cv[c];
        wsci[(size_t)slot * CAPQ + c] = s_ci[c];
    }
}

// ---- K2: per-batch sequential group chain on candidates (verified R6/R7) ---
__global__ __launch_bounds__(64) void dbs_final(
    const float* __restrict__ scores,   // (64,8,128)
    const float* __restrict__ overlap,  // (64,4,4)
    const int*   __restrict__ obi,      // (64,)
    const int*   __restrict__ lastn,    // (64,8,1)
    const int*   __restrict__ mask,     // (64,8,2)
    const int*   __restrict__ stepp,    // (1,)
    const int*   __restrict__ wscnt,
    const float* __restrict__ wscv,
    const int*   __restrict__ wsci,
    float*       __restrict__ out)      // 2560 floats
{
    const int b   = blockIdx.x;
    const int tid = threadIdx.x;
    const int step = stepp[0];
    const int ob   = obi[b];

    __shared__ float s_sc[BEAM];
    __shared__ int   s_valid[BEAM];
    __shared__ float s_pen[(NG-1)*KC];
    __shared__ int   s_penidx[(NG-1)*KC];
    __shared__ float s_selv[NG][KC];
    __shared__ int   s_seli[NG][KC];
    __shared__ int   s_selm[NG][KC];

    if (tid < BEAM) {
        const int* mk = mask + ((size_t)b * BEAM + tid) * NGRAM;
        s_valid[tid] = (mk[0] + mk[1]) == NGRAM;
        s_sc[tid]    = scores[((size_t)b * BEAM + tid) * TLEN + (step - 1)];
    }
    __syncthreads();

    for (int g = 0; g < NG; ++g) {
        if (tid == 0) {
            for (int j = 0; j < g; ++j) {
                const float pen = 1.0f + overlap[((size_t)ob * NG + g) * NG + j];
                s_penidx[j*KC + 0] = s_seli[j][0]; s_pen[j*KC + 0] = pen;
                s_penidx[j*KC + 1] = s_seli[j][1]; s_pen[j*KC + 1] = pen;
            }
        }
        __syncthreads();

        const int np = KC * g;            // block-uniform
        Top2 t; t2_init(t);
        for (int m = 0; m < MB; ++m) {
            const int beam = m * NG + g;
            if (s_valid[beam]) {          // block-uniform branch
                const int r = b * BEAM + beam;
                for (int qq = 0; qq < NQ; ++qq) {
                    const int slot = r * NQ + qq;
                    const int n = wscnt[slot];
                    for (int c = tid; c < n; c += 64) {
                        const float v   = wscv[(size_t)slot * CAPQ + c];
                        const int   idx = wsci[(size_t)slot * CAPQ + c];
                        float dv = 0.0f;
                        #pragma unroll
                        for (int p = 0; p < (NG-1)*KC; ++p)
                            if (p < np && s_penidx[p] == idx) dv += s_pen[p];
                        t2_push(t, v - 0.5f * dv + s_sc[beam], m * VOCAB + idx);
                    }
                }
            } else if (tid < KC) {
                // invalid row: constant sc -> best two flat idx m*V, m*V+1
                t2_push(t, s_sc[beam], m * VOCAB + tid);
            }
        }

        #pragma unroll
        for (int off = 32; off > 0; off >>= 1) {
            Top2 o;
            o.v1 = __shfl_down(t.v1, off); o.i1 = __shfl_down(t.i1, off);
            o.v2 = __shfl_down(t.v2, off); o.i2 = __shfl_down(t.i2, off);
            t2_merge(t, o);
        }
        if (tid == 0) {
            s_selv[g][0] = t.v1; s_seli[g][0] = t.i1 % VOCAB; s_selm[g][0] = t.i1 / VOCAB;
            s_selv[g][1] = t.v2; s_seli[g][1] = t.i2 % VOCAB; s_selm[g][1] = t.i2 / VOCAB;
        }
        __syncthreads();
    }

    // ---- outputs: scores[0,512) indices[512,1024) beams[1024,1536) overlap[1536,2560)
    if (tid < KC * NG) {                  // i = m*NG + g
        const int i = tid;
        const int m = i / NG, g = i % NG;
        out[(size_t)b * BEAM + i]        = s_selv[g][m];
        out[512 + (size_t)b * BEAM + i]  = (float)s_seli[g][m];
        out[1024 + (size_t)b * BEAM + i] = (float)(s_selm[g][m] * NG + g);
    }
    if (tid >= 16 && tid < 16 + NG * NG) {
        const int q  = tid - 16;
        const int g1 = q / NG, g2 = q % NG;
        int ov = 0;
        for (int m = 0; m < MB; ++m) {
            const int i1 = m * NG + g1, i2 = m * NG + g2;
            const int p1a = lastn[(size_t)b * BEAM + i1];
            const int p2a = lastn[(size_t)b * BEAM + i2];
            const int p1b = s_seli[g1][m];
            const int p2b = s_seli[g2][m];
            const int* mk1 = mask + ((size_t)b * BEAM + i1) * NGRAM;
            const int* mk2 = mask + ((size_t)b * BEAM + i2) * NGRAM;
            const bool e0 = (p1a == p2a) && (mk1[0] != 0) && (mk2[0] != 0);
            const bool e1 = (p1b == p2b) && (mk1[1] != 0) && (mk2[1] != 0);
            ov += (e0 && e1) ? 1 : 0;
        }
        out[1536 + (size_t)ob * (NG * NG) + q] =
            (overlap[(size_t)ob * (NG * NG) + q] + (float)ov) * 0.5f;
    }
}

extern "C" void kernel_launch(void* const* d_in, const int* in_sizes, int n_in,
                              void* d_out, int out_size, void* d_ws, size_t ws_size,
                              hipStream_t stream) {
    const float* lprobs  = (const float*)d_in[0];
    const float* scores  = (const float*)d_in[1];
    const float* overlap = (const float*)d_in[2];
    const int*   obi     = (const int*)d_in[3];
    const int*   lastn   = (const int*)d_in[4];
    const int*   mask    = (const int*)d_in[5];
    const int*   stepp   = (const int*)d_in[6];
    float*       out     = (float*)d_out;

    // ws layout: wscnt (2048 i32) | wscv (2048*CAPQ f32) | wsci (2048*CAPQ i32)
    int*   wscnt = (int*)d_ws;
    float* wscv  = (float*)((char*)d_ws + (size_t)ROWS * NQ * 4);
    int*   wsci  = (int*)((char*)d_ws + (size_t)ROWS * NQ * 4
                          + (size_t)ROWS * NQ * CAPQ * 4);

    dbs_candidates<<<ROWS * NQ, 256, 0, stream>>>(lprobs, mask, wscnt, wscv, wsci);
    dbs_final     <<<BSZ, 64, 0, stream>>>(scores, overlap, obi, lastn, mask, stepp,
                                           wscnt, wscv, wsci, out);
}

// Round 10
// 26.428 us; speedup vs baseline: 1.6205x; 1.3466x over previous
//
#include <hip/hip_runtime.h>
#include <math.h>

#define VOCAB 50257
#define BSZ   64
#define BEAM  8
#define NG    4     // NUM_GROUPS
#define MB    2     // beams per group
#define KC    2     // candidates per group
#define TLEN  128
#define NGRAM 2
#define SEG    64
#define SEGLEN 786               // 64*786 = 50304 >= 50257; n4 <= 196
#define ROWS  (BSZ * BEAM)       // 512
#define CAP   1024               // candidate capacity per row (E[cnt] ~ 34)

__device__ __forceinline__ bool better(float v1, int i1, float v2, int i2) {
    return (v1 > v2) || (v1 == v2 && i1 < i2);
}

struct Top2 { float v1, v2; int i1, i2; };

__device__ __forceinline__ void t2_init(Top2& t) {
    t.v1 = -INFINITY; t.v2 = -INFINITY; t.i1 = 0x7FFFFFFF; t.i2 = 0x7FFFFFFF;
}

__device__ __forceinline__ void t2_push(Top2& t, float v, int i) {
    if (better(v, i, t.v2, t.i2)) {
        if (better(v, i, t.v1, t.i1)) { t.v2 = t.v1; t.i2 = t.i1; t.v1 = v; t.i1 = i; }
        else                          { t.v2 = v;    t.i2 = i; }
    }
}

__device__ __forceinline__ void t2_merge(Top2& a, const Top2& b) {
    if (better(b.v1, b.i1, a.v1, a.i1)) {
        float nv2; int ni2;
        if (better(a.v1, a.i1, b.v2, b.i2)) { nv2 = a.v1; ni2 = a.i1; }
        else                                { nv2 = b.v2; ni2 = b.i2; }
        a.v1 = b.v1; a.i1 = b.i1; a.v2 = nv2; a.i2 = ni2;
    } else {
        if (better(b.v1, b.i1, a.v2, a.i2)) { a.v2 = b.v1; a.i2 = b.i1; }
    }
}

__device__ __forceinline__ float max4(float4 v) {
    return fmaxf(fmaxf(v.x, v.y), fmaxf(v.z, v.w));
}

// ------- Fused phase AB: block per row; segmax -> tau -> compact ------------
// R5 structure verbatim (best measured: 27.2us) + ONE change: pass 2 skips
// segments whose max < tau. Exact: such segments contain no element >= tau,
// and tau = 8th-largest segment max => exactly 8 of 64 segments rescanned.
__global__ __launch_bounds__(1024) void dbs_candidates(
    const float* __restrict__ lprobs,   // (512, 50257)
    const int*   __restrict__ mask,     // (512, 2)
    int*   __restrict__ wscnt,          // (512,)
    float* __restrict__ wscv,           // (512, CAP)
    int*   __restrict__ wsci)           // (512, CAP)
{
    const int r    = blockIdx.x;
    const int tid  = threadIdx.x;
    const int w    = tid >> 6, lane = tid & 63;

    if (mask[r * NGRAM] + mask[r * NGRAM + 1] != NGRAM) return;  // invalid row

    __shared__ float s_max[SEG];
    __shared__ float s_tau;
    __shared__ int   s_cnt;
    __shared__ float s_cv[CAP];
    __shared__ int   s_ci[CAP];

    if (tid == 0) s_cnt = 0;

    const size_t rowoff = (size_t)r * VOCAB;
    const float* row = lprobs + rowoff;

    // ---- pass 1: per-segment max (wave w owns segments 4w..4w+3) ----
    #pragma unroll
    for (int s = 0; s < 4; ++s) {
        const int seg   = w * 4 + s;
        const int start = seg * SEGLEN;
        const int end   = min(start + SEGLEN, VOCAB);
        const int mis   = (int)((rowoff + start) & 3);
        const int pre   = (4 - mis) & 3;

        float m = -INFINITY;
        if (lane < pre && start + lane < end) m = row[start + lane];
        const int vstart = start + pre;
        const int n4 = (end > vstart) ? ((end - vstart) >> 2) : 0;   // <= 196
        const float4* vrow = (const float4*)(row + vstart);

        float a0 = -INFINITY, a1 = -INFINITY, a2 = -INFINITY, a3 = -INFINITY;
        if (lane       < n4) a0 = max4(vrow[lane]);
        if (lane +  64 < n4) a1 = max4(vrow[lane + 64]);
        if (lane + 128 < n4) a2 = max4(vrow[lane + 128]);
        if (lane + 192 < n4) a3 = max4(vrow[lane + 192]);
        m = fmaxf(m, fmaxf(fmaxf(a0, a1), fmaxf(a2, a3)));
        const int tstart = vstart + 4 * n4;
        if (tstart + lane < end) m = fmaxf(m, row[tstart + lane]);

        #pragma unroll
        for (int off = 32; off > 0; off >>= 1) m = fmaxf(m, __shfl_xor(m, off));
        if (lane == 0) s_max[seg] = m;
    }
    __syncthreads();

    // ---- tau = 8th largest (lex) of the 64 segment maxima (wave 0) ----
    if (w == 0) {
        const float mym = s_max[lane];
        int rank = 0;
        for (int i = 0; i < SEG; ++i) {
            const float om = __shfl(mym, i);
            rank += better(om, i, mym, lane) ? 1 : 0;
        }
        if (rank == 7) s_tau = mym;     // exactly one lane (ranks are a permutation)
    }
    __syncthreads();
    const float tau = s_tau;

    // ---- pass 2: rescan ONLY segments with max >= tau (exactly 8 of 64) ----
    #pragma unroll
    for (int s = 0; s < 4; ++s) {
        const int seg   = w * 4 + s;
        if (s_max[seg] < tau) continue;              // wave-uniform exact skip
        const int start = seg * SEGLEN;
        const int end   = min(start + SEGLEN, VOCAB);
        const int mis   = (int)((rowoff + start) & 3);
        const int pre   = (4 - mis) & 3;

        if (lane < pre && start + lane < end) {
            const float v = row[start + lane];
            if (v >= tau) {
                const int p = atomicAdd(&s_cnt, 1);
                if (p < CAP) { s_cv[p] = v; s_ci[p] = start + lane; }
            }
        }
        const int vstart = start + pre;
        const int n4 = (end > vstart) ? ((end - vstart) >> 2) : 0;
        const float4* vrow = (const float4*)(row + vstart);

        #pragma unroll
        for (int u = 0; u < 4; ++u) {
            const int jj = lane + u * 64;
            if (jj < n4) {
                const float4 v = vrow[jj];
                if (max4(v) >= tau) {
                    const int base = vstart + 4 * jj;
                    #pragma unroll
                    for (int e = 0; e < 4; ++e) {
                        const float ve = (e == 0) ? v.x : (e == 1) ? v.y
                                       : (e == 2) ? v.z : v.w;
                        if (ve >= tau) {
                            const int p = atomicAdd(&s_cnt, 1);
                            if (p < CAP) { s_cv[p] = ve; s_ci[p] = base + e; }
                        }
                    }
                }
            }
        }
        const int tstart = vstart + 4 * n4;
        if (tstart + lane < end) {
            const float v = row[tstart + lane];
            if (v >= tau) {
                const int p = atomicAdd(&s_cnt, 1);
                if (p < CAP) { s_cv[p] = v; s_ci[p] = tstart + lane; }
            }
        }
    }
    __syncthreads();

    // ---- emit: count + coalesced candidate dump ----
    const int cnt = min(s_cnt, CAP);
    if (tid == 0) wscnt[r] = cnt;
    for (int c = tid; c < cnt; c += 1024) {
        wscv[(size_t)r * CAP + c] = s_cv[c];
        wsci[(size_t)r * CAP + c] = s_ci[c];
    }
}

// ---------- Final: per-batch sequential group chain on candidates -----------
__global__ __launch_bounds__(64) void dbs_final(
    const float* __restrict__ scores,   // (64,8,128)
    const float* __restrict__ overlap,  // (64,4,4)
    const int*   __restrict__ obi,      // (64,)
    const int*   __restrict__ lastn,    // (64,8,1)
    const int*   __restrict__ mask,     // (64,8,2)
    const int*   __restrict__ stepp,    // (1,)
    const int*   __restrict__ wscnt,
    const float* __restrict__ wscv,
    const int*   __restrict__ wsci,
    float*       __restrict__ out)      // 2560 floats
{
    const int b   = blockIdx.x;
    const int tid = threadIdx.x;
    const int step = stepp[0];
    const int ob   = obi[b];

    __shared__ float s_sc[BEAM];
    __shared__ int   s_valid[BEAM];
    __shared__ float s_pen[(NG-1)*KC];
    __shared__ int   s_penidx[(NG-1)*KC];
    __shared__ float s_selv[NG][KC];
    __shared__ int   s_seli[NG][KC];
    __shared__ int   s_selm[NG][KC];

    if (tid < BEAM) {
        const int* mk = mask + ((size_t)b * BEAM + tid) * NGRAM;
        s_valid[tid] = (mk[0] + mk[1]) == NGRAM;
        s_sc[tid]    = scores[((size_t)b * BEAM + tid) * TLEN + (step - 1)];
    }
    __syncthreads();

    for (int g = 0; g < NG; ++g) {
        if (tid == 0) {
            for (int j = 0; j < g; ++j) {
                const float pen = 1.0f + overlap[((size_t)ob * NG + g) * NG + j];
                s_penidx[j*KC + 0] = s_seli[j][0]; s_pen[j*KC + 0] = pen;
                s_penidx[j*KC + 1] = s_seli[j][1]; s_pen[j*KC + 1] = pen;
            }
        }
        __syncthreads();

        const int np = KC * g;            // block-uniform
        Top2 t; t2_init(t);
        for (int m = 0; m < MB; ++m) {
            const int beam = m * NG + g;
            if (s_valid[beam]) {          // block-uniform branch
                const int r = b * BEAM + beam;
                const int n = wscnt[r];
                for (int c = tid; c < n; c += 64) {
                    const float v   = wscv[(size_t)r * CAP + c];
                    const int   idx = wsci[(size_t)r * CAP + c];
                    float dv = 0.0f;
                    #pragma unroll
                    for (int p = 0; p < (NG-1)*KC; ++p)
                        if (p < np && s_penidx[p] == idx) dv += s_pen[p];
                    t2_push(t, v - 0.5f * dv + s_sc[beam], m * VOCAB + idx);
                }
            } else if (tid < KC) {
                // invalid row: constant sc -> best two flat idx m*V, m*V+1
                t2_push(t, s_sc[beam], m * VOCAB + tid);
            }
        }

        #pragma unroll
        for (int off = 32; off > 0; off >>= 1) {
            Top2 o;
            o.v1 = __shfl_down(t.v1, off); o.i1 = __shfl_down(t.i1, off);
            o.v2 = __shfl_down(t.v2, off); o.i2 = __shfl_down(t.i2, off);
            t2_merge(t, o);
        }
        if (tid == 0) {
            s_selv[g][0] = t.v1; s_seli[g][0] = t.i1 % VOCAB; s_selm[g][0] = t.i1 / VOCAB;
            s_selv[g][1] = t.v2; s_seli[g][1] = t.i2 % VOCAB; s_selm[g][1] = t.i2 / VOCAB;
        }
        __syncthreads();
    }

    // ---- outputs: scores[0,512) indices[512,1024) beams[1024,1536) overlap[1536,2560)
    if (tid < KC * NG) {                  // i = m*NG + g
        const int i = tid;
        const int m = i / NG, g = i % NG;
        out[(size_t)b * BEAM + i]        = s_selv[g][m];
        out[512 + (size_t)b * BEAM + i]  = (float)s_seli[g][m];
        out[1024 + (size_t)b * BEAM + i] = (float)(s_selm[g][m] * NG + g);
    }
    if (tid >= 16 && tid < 16 + NG * NG) {
        const int q  = tid - 16;
        const int g1 = q / NG, g2 = q % NG;
        int ov = 0;
        for (int m = 0; m < MB; ++m) {
            const int i1 = m * NG + g1, i2 = m * NG + g2;
            const int p1a = lastn[(size_t)b * BEAM + i1];
            const int p2a = lastn[(size_t)b * BEAM + i2];
            const int p1b = s_seli[g1][m];
            const int p2b = s_seli[g2][m];
            const int* mk1 = mask + ((size_t)b * BEAM + i1) * NGRAM;
            const int* mk2 = mask + ((size_t)b * BEAM + i2) * NGRAM;
            const bool e0 = (p1a == p2a) && (mk1[0] != 0) && (mk2[0] != 0);
            const bool e1 = (p1b == p2b) && (mk1[1] != 0) && (mk2[1] != 0);
            ov += (e0 && e1) ? 1 : 0;
        }
        out[1536 + (size_t)ob * (NG * NG) + q] =
            (overlap[(size_t)ob * (NG * NG) + q] + (float)ov) * 0.5f;
    }
}

extern "C" void kernel_launch(void* const* d_in, const int* in_sizes, int n_in,
                              void* d_out, int out_size, void* d_ws, size_t ws_size,
                              hipStream_t stream) {
    const float* lprobs  = (const float*)d_in[0];
    const float* scores  = (const float*)d_in[1];
    const float* overlap = (const float*)d_in[2];
    const int*   obi     = (const int*)d_in[3];
    const int*   lastn   = (const int*)d_in[4];
    const int*   mask    = (const int*)d_in[5];
    const int*   stepp   = (const int*)d_in[6];
    float*       out     = (float*)d_out;

    // ws layout: wscnt (512 i32) | wscv (512*CAP f32) | wsci (512*CAP i32)
    int*   wscnt = (int*)d_ws;
    float* wscv  = (float*)((char*)d_ws + ROWS * 4);
    int*   wsci  = (int*)((char*)d_ws + ROWS * 4 + (size_t)ROWS * CAP * 4);

    dbs_candidates<<<ROWS, 1024, 0, stream>>>(lprobs, mask, wscnt, wscv, wsci);
    dbs_final     <<<BSZ, 64, 0, stream>>>(scores, overlap, obi, lastn, mask, stepp,
                                           wscnt, wscv, wsci, out);
}

// Round 11
// 25.777 us; speedup vs baseline: 1.6614x; 1.0253x over previous
//
#include <hip/hip_runtime.h>
#include <math.h>

#define VOCAB 50257
#define BSZ   64
#define BEAM  8
#define NG    4     // NUM_GROUPS
#define MB    2     // beams per group
#define KC    2     // candidates per group
#define TLEN  128
#define NGRAM 2
#define SEG    64
#define SEGLEN 786               // 64*786 = 50304 >= 50257
#define ROWS  (BSZ * BEAM)       // 512
#define MAXK  8                  // max slices per row
#define CAPQ  256                // candidate capacity per slice

__device__ __forceinline__ bool better(float v1, int i1, float v2, int i2) {
    return (v1 > v2) || (v1 == v2 && i1 < i2);
}

struct Top2 { float v1, v2; int i1, i2; };

__device__ __forceinline__ void t2_init(Top2& t) {
    t.v1 = -INFINITY; t.v2 = -INFINITY; t.i1 = 0x7FFFFFFF; t.i2 = 0x7FFFFFFF;
}

__device__ __forceinline__ void t2_push(Top2& t, float v, int i) {
    if (better(v, i, t.v2, t.i2)) {
        if (better(v, i, t.v1, t.i1)) { t.v2 = t.v1; t.i2 = t.i1; t.v1 = v; t.i1 = i; }
        else                          { t.v2 = v;    t.i2 = i; }
    }
}

__device__ __forceinline__ void t2_merge(Top2& a, const Top2& b) {
    if (better(b.v1, b.i1, a.v1, a.i1)) {
        float nv2; int ni2;
        if (better(a.v1, a.i1, b.v2, b.i2)) { nv2 = a.v1; ni2 = a.i1; }
        else                                { nv2 = b.v2; ni2 = b.i2; }
        a.v1 = b.v1; a.i1 = b.i1; a.v2 = nv2; a.i2 = ni2;
    } else {
        if (better(b.v1, b.i1, a.v2, a.i2)) { a.v2 = b.v1; a.i2 = b.i1; }
    }
}

__device__ __forceinline__ float max4(float4 v) {
    return fmaxf(fmaxf(v.x, v.y), fmaxf(v.z, v.w));
}

// ---- Scan: adaptive worklist; block = (valid-row ordinal, slice) -----------
// Every block builds the same validity bitmask from mask (deterministic),
// derives k = slices/row (pow2 <= 512/nvalid, capped 8), so the nv*k working
// blocks are the FIRST block IDs -> round-robin over CUs -> balanced HBM pull.
__global__ __launch_bounds__(1024, 8) void dbs_candidates(
    const float* __restrict__ lprobs,   // (512, 50257)
    const int*   __restrict__ mask,     // (512, 2)
    int*   __restrict__ meta,           // [0] = k
    int*   __restrict__ wscnt,          // (512*MAXK,)
    float* __restrict__ wscv,           // (512*MAXK, CAPQ)
    int*   __restrict__ wsci)           // (512*MAXK, CAPQ)
{
    const int tid  = threadIdx.x;
    const int w    = tid >> 6, lane = tid & 63;

    __shared__ unsigned long long s_bits[8];
    __shared__ float s_max[16];
    __shared__ float s_tau;
    __shared__ int   s_cnt;
    __shared__ float s_cv[CAPQ];
    __shared__ int   s_ci[CAPQ];

    // ---- classify all 512 rows (thread t -> row t), ballot into LDS ----
    bool validp = false;
    if (tid < ROWS) {
        const int2 mk = ((const int2*)mask)[tid];
        validp = (mk.x + mk.y) == NGRAM;
    }
    const unsigned long long bm = __ballot(validp);
    if (w < 8 && lane == 0) s_bits[w] = bm;
    if (tid == 0) s_cnt = 0;
    __syncthreads();

    int nv = 0;
    #pragma unroll
    for (int i = 0; i < 8; ++i) nv += __popcll(s_bits[i]);
    int k = 1;
    if (nv > 0) {
        const int q = ROWS / nv;        // 512/nv >= 1
        k = (q >= 8) ? 8 : (q >= 4) ? 4 : (q >= 2) ? 2 : 1;
    }
    if (blockIdx.x == 0 && tid == 0) meta[0] = k;
    const int b = blockIdx.x;
    if (b >= nv * k) return;

    // ---- map b -> (r = vidx-th valid row, slice) ----
    const int vidx  = b / k;
    const int slice = b - vidx * k;
    int r = 0, cnt = 0;
    for (int i = 0; i < 8; ++i) {
        const unsigned long long x = s_bits[i];
        const int c = __popcll(x);
        if (cnt + c > vidx) {
            unsigned long long y = x;
            for (int need = vidx - cnt; need > 0; --need) y &= y - 1;
            r = i * 64 + (__ffsll((unsigned long long)y) - 1);
            break;
        }
        cnt += c;
    }

    const size_t rowoff = (size_t)r * VOCAB;
    const float* row = lprobs + rowoff;

    // slice vocab range; 16 per-wave sub-segments
    const int segs = SEG / k;
    const int A    = slice * segs * SEGLEN;
    const int B    = min(A + segs * SEGLEN, VOCAB);
    const int L    = B - A;
    const int subL = (L + 15) >> 4;     // all 16 sub-segments nonempty (L>240)

    // ---- pass 1: per-sub-segment max (wave w owns sub-segment w) ----
    {
        const int start = A + w * subL;
        const int end   = min(start + subL, B);
        float m = -INFINITY;
        if (start < end) {
            const int mis = (int)((rowoff + start) & 3);
            int pre = (4 - mis) & 3;
            if (pre > end - start) pre = end - start;
            if (lane < pre) m = row[start + lane];
            const int vstart = start + pre;
            const int n4 = (end > vstart) ? ((end - vstart) >> 2) : 0;
            const float4* vrow = (const float4*)(row + vstart);

            float a0 = -INFINITY, a1 = -INFINITY, a2 = -INFINITY, a3 = -INFINITY;
            int jj = lane;
            for (; jj + 192 < n4; jj += 256) {
                a0 = fmaxf(a0, max4(vrow[jj]));
                a1 = fmaxf(a1, max4(vrow[jj + 64]));
                a2 = fmaxf(a2, max4(vrow[jj + 128]));
                a3 = fmaxf(a3, max4(vrow[jj + 192]));
            }
            for (; jj < n4; jj += 64) a0 = fmaxf(a0, max4(vrow[jj]));
            m = fmaxf(m, fmaxf(fmaxf(a0, a1), fmaxf(a2, a3)));
            const int tstart = vstart + 4 * n4;
            if (tstart + lane < end) m = fmaxf(m, row[tstart + lane]);
        }
        #pragma unroll
        for (int off = 32; off > 0; off >>= 1) m = fmaxf(m, __shfl_xor(m, off));
        if (lane == 0) s_max[w] = m;
    }
    __syncthreads();

    // ---- tau = 8th largest (lex) of the 16 sub-maxima: >=8 elems >= tau ----
    if (w == 0) {
        const float mym = (lane < 16) ? s_max[lane] : -INFINITY;
        int rank = 0;
        #pragma unroll
        for (int i = 0; i < 16; ++i) {
            const float om = __shfl(mym, i);
            rank += better(om, i, mym, lane) ? 1 : 0;
        }
        if (lane < 16 && rank == 7) s_tau = mym;    // ranks are a permutation
    }
    __syncthreads();
    const float tau = s_tau;

    // ---- pass 2: rescan only sub-segments with max >= tau (exactly 8) ----
    if (s_max[w] >= tau) {
        const int start = A + w * subL;
        const int end   = min(start + subL, B);
        if (start < end) {
            const int mis = (int)((rowoff + start) & 3);
            int pre = (4 - mis) & 3;
            if (pre > end - start) pre = end - start;
            if (lane < pre) {
                const float v = row[start + lane];
                if (v >= tau) {
                    const int p = atomicAdd(&s_cnt, 1);
                    if (p < CAPQ) { s_cv[p] = v; s_ci[p] = start + lane; }
                }
            }
            const int vstart = start + pre;
            const int n4 = (end > vstart) ? ((end - vstart) >> 2) : 0;
            const float4* vrow = (const float4*)(row + vstart);

            for (int jj = lane; jj < n4; jj += 64) {
                const float4 v = vrow[jj];
                if (max4(v) >= tau) {
                    const int base = vstart + 4 * jj;
                    #pragma unroll
                    for (int e = 0; e < 4; ++e) {
                        const float ve = (e == 0) ? v.x : (e == 1) ? v.y
                                       : (e == 2) ? v.z : v.w;
                        if (ve >= tau) {
                            const int p = atomicAdd(&s_cnt, 1);
                            if (p < CAPQ) { s_cv[p] = ve; s_ci[p] = base + e; }
                        }
                    }
                }
            }
            const int tstart = vstart + 4 * n4;
            if (tstart + lane < end) {
                const float v = row[tstart + lane];
                if (v >= tau) {
                    const int p = atomicAdd(&s_cnt, 1);
                    if (p < CAPQ) { s_cv[p] = v; s_ci[p] = tstart + lane; }
                }
            }
        }
    }
    __syncthreads();

    // ---- emit ----
    const int ccnt = min(s_cnt, CAPQ);
    const int slot = r * MAXK + slice;
    if (tid == 0) wscnt[slot] = ccnt;
    for (int c = tid; c < ccnt; c += 1024) {
        wscv[(size_t)slot * CAPQ + c] = s_cv[c];
        wsci[(size_t)slot * CAPQ + c] = s_ci[c];
    }
}

// ---------- Final: per-batch sequential group chain on candidates -----------
__global__ __launch_bounds__(64) void dbs_final(
    const float* __restrict__ scores,   // (64,8,128)
    const float* __restrict__ overlap,  // (64,4,4)
    const int*   __restrict__ obi,      // (64,)
    const int*   __restrict__ lastn,    // (64,8,1)
    const int*   __restrict__ mask,     // (64,8,2)
    const int*   __restrict__ stepp,    // (1,)
    const int*   __restrict__ meta,
    const int*   __restrict__ wscnt,
    const float* __restrict__ wscv,
    const int*   __restrict__ wsci,
    float*       __restrict__ out)      // 2560 floats
{
    const int b   = blockIdx.x;
    const int tid = threadIdx.x;
    const int step = stepp[0];
    const int ob   = obi[b];

    __shared__ float s_sc[BEAM];
    __shared__ int   s_valid[BEAM];
    __shared__ int   s_k;
    __shared__ float s_pen[(NG-1)*KC];
    __shared__ int   s_penidx[(NG-1)*KC];
    __shared__ float s_selv[NG][KC];
    __shared__ int   s_seli[NG][KC];
    __shared__ int   s_selm[NG][KC];

    if (tid < BEAM) {
        const int* mk = mask + ((size_t)b * BEAM + tid) * NGRAM;
        s_valid[tid] = (mk[0] + mk[1]) == NGRAM;
        s_sc[tid]    = scores[((size_t)b * BEAM + tid) * TLEN + (step - 1)];
    }
    if (tid == 0) s_k = meta[0];
    __syncthreads();
    const int k = s_k;

    for (int g = 0; g < NG; ++g) {
        if (tid == 0) {
            for (int j = 0; j < g; ++j) {
                const float pen = 1.0f + overlap[((size_t)ob * NG + g) * NG + j];
                s_penidx[j*KC + 0] = s_seli[j][0]; s_pen[j*KC + 0] = pen;
                s_penidx[j*KC + 1] = s_seli[j][1]; s_pen[j*KC + 1] = pen;
            }
        }
        __syncthreads();

        const int np = KC * g;            // block-uniform
        Top2 t; t2_init(t);
        for (int m = 0; m < MB; ++m) {
            const int beam = m * NG + g;
            if (s_valid[beam]) {          // block-uniform branch
                const int r = b * BEAM + beam;
                for (int qq = 0; qq < k; ++qq) {
                    const int slot = r * MAXK + qq;
                    const int n = wscnt[slot];
                    for (int c = tid; c < n; c += 64) {
                        const float v   = wscv[(size_t)slot * CAPQ + c];
                        const int   idx = wsci[(size_t)slot * CAPQ + c];
                        float dv = 0.0f;
                        #pragma unroll
                        for (int p = 0; p < (NG-1)*KC; ++p)
                            if (p < np && s_penidx[p] == idx) dv += s_pen[p];
                        t2_push(t, v - 0.5f * dv + s_sc[beam], m * VOCAB + idx);
                    }
                }
            } else if (tid < KC) {
                // invalid row: constant sc -> best two flat idx m*V, m*V+1
                t2_push(t, s_sc[beam], m * VOCAB + tid);
            }
        }

        #pragma unroll
        for (int off = 32; off > 0; off >>= 1) {
            Top2 o;
            o.v1 = __shfl_down(t.v1, off); o.i1 = __shfl_down(t.i1, off);
            o.v2 = __shfl_down(t.v2, off); o.i2 = __shfl_down(t.i2, off);
            t2_merge(t, o);
        }
        if (tid == 0) {
            s_selv[g][0] = t.v1; s_seli[g][0] = t.i1 % VOCAB; s_selm[g][0] = t.i1 / VOCAB;
            s_selv[g][1] = t.v2; s_seli[g][1] = t.i2 % VOCAB; s_selm[g][1] = t.i2 / VOCAB;
        }
        __syncthreads();
    }

    // ---- outputs: scores[0,512) indices[512,1024) beams[1024,1536) overlap[1536,2560)
    if (tid < KC * NG) {                  // i = m*NG + g
        const int i = tid;
        const int m = i / NG, g = i % NG;
        out[(size_t)b * BEAM + i]        = s_selv[g][m];
        out[512 + (size_t)b * BEAM + i]  = (float)s_seli[g][m];
        out[1024 + (size_t)b * BEAM + i] = (float)(s_selm[g][m] * NG + g);
    }
    if (tid >= 16 && tid < 16 + NG * NG) {
        const int q  = tid - 16;
        const int g1 = q / NG, g2 = q % NG;
        int ov = 0;
        for (int m = 0; m < MB; ++m) {
            const int i1 = m * NG + g1, i2 = m * NG + g2;
            const int p1a = lastn[(size_t)b * BEAM + i1];
            const int p2a = lastn[(size_t)b * BEAM + i2];
            const int p1b = s_seli[g1][m];
            const int p2b = s_seli[g2][m];
            const int* mk1 = mask + ((size_t)b * BEAM + i1) * NGRAM;
            const int* mk2 = mask + ((size_t)b * BEAM + i2) * NGRAM;
            const bool e0 = (p1a == p2a) && (mk1[0] != 0) && (mk2[0] != 0);
            const bool e1 = (p1b == p2b) && (mk1[1] != 0) && (mk2[1] != 0);
            ov += (e0 && e1) ? 1 : 0;
        }
        out[1536 + (size_t)ob * (NG * NG) + q] =
            (overlap[(size_t)ob * (NG * NG) + q] + (float)ov) * 0.5f;
    }
}

extern "C" void kernel_launch(void* const* d_in, const int* in_sizes, int n_in,
                              void* d_out, int out_size, void* d_ws, size_t ws_size,
                              hipStream_t stream) {
    const float* lprobs  = (const float*)d_in[0];
    const float* scores  = (const float*)d_in[1];
    const float* overlap = (const float*)d_in[2];
    const int*   obi     = (const int*)d_in[3];
    const int*   lastn   = (const int*)d_in[4];
    const int*   mask    = (const int*)d_in[5];
    const int*   stepp   = (const int*)d_in[6];
    float*       out     = (float*)d_out;

    // ws: meta(16 i32) | wscnt(512*MAXK i32) | wscv | wsci
    int*   meta  = (int*)d_ws;
    int*   wscnt = (int*)((char*)d_ws + 64);
    float* wscv  = (float*)((char*)d_ws + 64 + (size_t)ROWS * MAXK * 4);
    int*   wsci  = (int*)((char*)d_ws + 64 + (size_t)ROWS * MAXK * 4
                          + (size_t)ROWS * MAXK * CAPQ * 4);

    dbs_candidates<<<ROWS, 1024, 0, stream>>>(lprobs, mask, meta, wscnt, wscv, wsci);
    dbs_final     <<<BSZ, 64, 0, stream>>>(scores, overlap, obi, lastn, mask, stepp,
                                           meta, wscnt, wscv, wsci, out);
}